// Round 1
// 195.782 us; speedup vs baseline: 1.1770x; 1.1770x over previous
//
#include <hip/hip_runtime.h>

// cAttention B=8, C=16, L=512, D=256 (fp32 in/out).
// R6: - convert_x kernel ELIMINATED: ca_fused reads x fp32 directly, converts
//       in-register into a resident LDS tile xs[32][264] used by BOTH stages.
//     - Es (33.3 KB) aliases the Bs staging buffer (union) -> LDS 69.6->51.4 KB
//       -> 3 blocks/CU (was 2).
//     - Weights pre-transposed to k-quad-major W_t[k>>3][n][8] so MFMA
//       B-fragment ds_read_b128 is conflict-free (was 8-way per quarter-wave).
//     - K-loop: ds_read frags -> barrier -> issue next global_load_lds -> MFMA
//       -> barrier (next tile in flight under MFMA).

typedef __attribute__((ext_vector_type(8))) short bf16x8;
typedef __attribute__((ext_vector_type(4))) float f32x4;
typedef __attribute__((ext_vector_type(8))) _Float16 h16x8;
typedef __attribute__((ext_vector_type(4))) _Float16 h16x4;
typedef const __attribute__((address_space(1))) void* gp1_t;
typedef __attribute__((address_space(3))) void* lp3_t;

__device__ __forceinline__ unsigned short f2bf(float f) {
  union { float f; unsigned int u; } v; v.f = f;
  return (unsigned short)((v.u + 0x7FFFu + ((v.u >> 16) & 1u)) >> 16);
}

// ---- prep: Wqb_t = transpose-pack(Wqkv[0:512]) ; Wcomb_t = pack(Wout @ Wv) ;
//      bcomb = Wout @ bv.  Layout: W_t[k>>3][n][8] (8 consecutive k packed). ----
__global__ __launch_bounds__(256) void ca_prep_kernel(
    const float* __restrict__ Wqkv, const float* __restrict__ Wout,
    const float* __restrict__ bqkv,
    unsigned short* __restrict__ Wqb_t, unsigned short* __restrict__ Wcb_t,
    float* __restrict__ bcomb) {
  const int blk = blockIdx.x;
  if (blk < 64) {
    // convert+transpose Wqkv (512x256 f32) -> Wqb_t[k8][512][8] bf16
    const int t = blk * 256 + threadIdx.x;  // 16384 threads
    const int k8 = t >> 9, n = t & 511;
    const float* src = Wqkv + (size_t)n * 256 + k8 * 8;
    const float4 v0 = *(const float4*)src;
    const float4 v1 = *(const float4*)(src + 4);
    bf16x8 o;
    o[0] = (short)f2bf(v0.x); o[1] = (short)f2bf(v0.y);
    o[2] = (short)f2bf(v0.z); o[3] = (short)f2bf(v0.w);
    o[4] = (short)f2bf(v1.x); o[5] = (short)f2bf(v1.y);
    o[6] = (short)f2bf(v1.z); o[7] = (short)f2bf(v1.w);
    *(bf16x8*)(Wqb_t + (size_t)t * 8) = o;  // t = k8*512 + n: coalesced store
    return;
  }
  const int dp = blk - 64;       // output row n (0..255)
  const int e = threadIdx.x;     // k (0..255)
  const float* wrow = Wout + (size_t)dp * 256;
  float acc = 0.f;
  for (int f = 0; f < 256; ++f)
    acc = fmaf(wrow[f], Wqkv[(size_t)(512 + f) * 256 + e], acc);
  Wcb_t[((size_t)(e >> 3) * 256 + dp) * 8 + (e & 7)] = f2bf(acc);
  if (e == 0) {
    float b = 0.f;
    for (int f = 0; f < 256; ++f) b = fmaf(wrow[f], bqkv[512 + f], b);
    bcomb[dp] = b;
  }
}

// ---- fused: qk MFMA + exp + score + softmax diag + out MFMA ----
__global__ __launch_bounds__(512, 6) void ca_fused(
    const float* __restrict__ x,             // (8,16,512,256) fp32
    const unsigned short* __restrict__ Wqb_t,  // [32][512][8] bf16
    const unsigned short* __restrict__ Wcb_t,  // [32][256][8] bf16
    const float* __restrict__ bqkv, const float* __restrict__ bh,
    const float* __restrict__ Vw,
    const float* __restrict__ bcomb, const float* __restrict__ bout,
    float* __restrict__ out) {
  __shared__ __align__(16) unsigned short xs[32 * 264];  // 16.9 KB resident A tile
  __shared__ __align__(16) unsigned short BsEs[16640];   // 33.3 KB: Bs / Es alias
  __shared__ __align__(16) float vw_s[256];
  __shared__ float af_s[32];
  unsigned short* const Bs = BsEs;          // staging: [quad][n][8] per k-chunk
  _Float16* const Es = (_Float16*)BsEs;     // 32 rows x 520 (512 + pad)

  const int tid = threadIdx.x;
  const int lane = tid & 63, wave = tid >> 6;
  const int quad = lane >> 4, l15 = lane & 15;
  const int rt0 = blockIdx.x * 32;          // global xf row base

  if (tid < 256) vw_s[tid] = -2.f * Vw[tid];

  // issue stage1 k0c=0 B loads (2048 x 16B segs, lane-linear into Bs)
#pragma unroll
  for (int i = 0; i < 4; ++i) {
    const int sb = wave * 256 + i * 64;
    const unsigned short* g = Wqb_t + (size_t)(sb + lane) * 8;
    __builtin_amdgcn_global_load_lds((gp1_t)g, (lp3_t)(Bs + sb * 8), 16, 0, 0);
  }

  // x tile: 32 rows x 256 fp32 -> bf16 -> xs (row stride 264: 2-way-free reads)
  {
    const int rl = tid >> 4, c0 = (tid & 15) * 16;
    const int r = rt0 + rl;
    const int b = r >> 13, l = (r >> 4) & 511, c = r & 15;
    const float* src = x + ((size_t)(b * 16 + c) * 512 + l) * 256 + c0;
    unsigned short* dst = xs + rl * 264 + c0;
#pragma unroll
    for (int j = 0; j < 2; ++j) {
      const float4 v0 = *(const float4*)(src + j * 8);
      const float4 v1 = *(const float4*)(src + j * 8 + 4);
      bf16x8 o;
      o[0] = (short)f2bf(v0.x); o[1] = (short)f2bf(v0.y);
      o[2] = (short)f2bf(v0.z); o[3] = (short)f2bf(v0.w);
      o[4] = (short)f2bf(v1.x); o[5] = (short)f2bf(v1.y);
      o[6] = (short)f2bf(v1.z); o[7] = (short)f2bf(v1.w);
      *(bf16x8*)(dst + j * 8) = o;
    }
  }
  __syncthreads();  // xs ready; k0c=0 B tile landed (barrier drains vmcnt)

  // ---------- stage 1: E[32 x 512] ----------
  f32x4 acc[2][4] = {};
  for (int k0c = 0; k0c < 8; ++k0c) {
    bf16x8 af[2], bfr[4];
#pragma unroll
    for (int mi = 0; mi < 2; ++mi)
      af[mi] = *(const bf16x8*)&xs[(mi * 16 + l15) * 264 + k0c * 32 + quad * 8];
#pragma unroll
    for (int ni = 0; ni < 4; ++ni)
      bfr[ni] = *(const bf16x8*)&Bs[(quad * 512 + wave * 64 + ni * 16 + l15) * 8];
    __syncthreads();  // frags in regs; Bs free for next tile
    if (k0c < 7) {
#pragma unroll
      for (int i = 0; i < 4; ++i) {
        const int sb = wave * 256 + i * 64;
        const unsigned short* g =
            Wqb_t + ((size_t)(k0c + 1) * 2048 + sb + lane) * 8;
        __builtin_amdgcn_global_load_lds((gp1_t)g, (lp3_t)(Bs + sb * 8), 16, 0, 0);
      }
    }
#pragma unroll
    for (int mi = 0; mi < 2; ++mi)
#pragma unroll
      for (int ni = 0; ni < 4; ++ni)
        acc[mi][ni] = __builtin_amdgcn_mfma_f32_16x16x32_bf16(
            bfr[ni], af[mi], acc[mi][ni], 0, 0, 0);
    __syncthreads();  // drains vmcnt: next tile ready
  }

  // stage-1 epilogue: E = exp2(clamp((acc+bias)*2log2e, +-15)) -> Es (over Bs)
  const float SC = 2.8853900817779268f;  // 2*log2(e)
  const bool isq = (wave < 4);           // n < 256 -> q part (gets bh)
#pragma unroll
  for (int mi = 0; mi < 2; ++mi) {
    const int rl = mi * 16 + l15;
#pragma unroll
    for (int ni = 0; ni < 4; ++ni) {
      const int n = wave * 64 + ni * 16 + quad * 4;
      const float4 bq = *(const float4*)(bqkv + n);
      float4 bhv = make_float4(0.f, 0.f, 0.f, 0.f);
      if (isq) bhv = *(const float4*)(bh + n);
      h16x4 st;
      st[0] = (_Float16)__builtin_amdgcn_exp2f(
          fminf(15.f, fmaxf(-15.f, (acc[mi][ni][0] + bq.x + bhv.x) * SC)));
      st[1] = (_Float16)__builtin_amdgcn_exp2f(
          fminf(15.f, fmaxf(-15.f, (acc[mi][ni][1] + bq.y + bhv.y) * SC)));
      st[2] = (_Float16)__builtin_amdgcn_exp2f(
          fminf(15.f, fmaxf(-15.f, (acc[mi][ni][2] + bq.z + bhv.z) * SC)));
      st[3] = (_Float16)__builtin_amdgcn_exp2f(
          fminf(15.f, fmaxf(-15.f, (acc[mi][ni][3] + bq.w + bhv.w) * SC)));
      *(h16x4*)&Es[rl * 520 + n] = st;
    }
  }
  __syncthreads();  // Es visible to all waves

  // ---------- score: 1 score/thread ----------
  {
    const int p = tid >> 8, qc = (tid >> 4) & 15, kc = tid & 15;
    const _Float16* eqp = Es + (p * 16 + qc) * 520;
    const _Float16* ekp = Es + (p * 16 + kc) * 520 + 256;
    f32x4 a4 = {};
#pragma unroll 4
    for (int d = 0; d < 256; d += 8) {
      const h16x8 eq = *(const h16x8*)(eqp + d);
      const h16x8 ek = *(const h16x8*)(ekp + d);
      const f32x4 wv0 = *(const f32x4*)(vw_s + d);
      const f32x4 wv1 = *(const f32x4*)(vw_s + d + 4);
      f32x4 sg0, sg1;
      sg0.x = __builtin_amdgcn_rcpf(1.f + (float)eq[0] * (float)ek[0]);
      sg0.y = __builtin_amdgcn_rcpf(1.f + (float)eq[1] * (float)ek[1]);
      sg0.z = __builtin_amdgcn_rcpf(1.f + (float)eq[2] * (float)ek[2]);
      sg0.w = __builtin_amdgcn_rcpf(1.f + (float)eq[3] * (float)ek[3]);
      sg1.x = __builtin_amdgcn_rcpf(1.f + (float)eq[4] * (float)ek[4]);
      sg1.y = __builtin_amdgcn_rcpf(1.f + (float)eq[5] * (float)ek[5]);
      sg1.z = __builtin_amdgcn_rcpf(1.f + (float)eq[6] * (float)ek[6]);
      sg1.w = __builtin_amdgcn_rcpf(1.f + (float)eq[7] * (float)ek[7]);
      a4 += wv0 * sg0 + wv1 * sg1;
    }
    float s = (a4[0] + a4[1]) + (a4[2] + a4[3]);
    float m = s;
    for (int off = 8; off; off >>= 1) m = fmaxf(m, __shfl_xor(m, off, 16));
    const float e = __builtin_amdgcn_exp2f((s - m) * 1.4426950408889634f);
    float sum = e;
    for (int off = 8; off; off >>= 1) sum += __shfl_xor(sum, off, 16);
    if (kc == qc) af_s[p * 16 + qc] = e / sum;
  }
  __syncthreads();  // all Es reads done; af_s written -> Bs region reusable

  // stage2 k0c=0 loads (1024 x 16B segs into Bs, overwriting Es)
#pragma unroll
  for (int i = 0; i < 2; ++i) {
    const int sb = wave * 128 + i * 64;
    const unsigned short* g = Wcb_t + (size_t)(sb + lane) * 8;
    __builtin_amdgcn_global_load_lds((gp1_t)g, (lp3_t)(Bs + sb * 8), 16, 0, 0);
  }
  __syncthreads();  // k0c=0 tile landed

  // ---------- stage 2: out[32 x 256] ----------
  f32x4 acc2[2][2] = {};
  for (int k0c = 0; k0c < 8; ++k0c) {
    bf16x8 af[2], bfr[2];
#pragma unroll
    for (int mi = 0; mi < 2; ++mi)
      af[mi] = *(const bf16x8*)&xs[(mi * 16 + l15) * 264 + k0c * 32 + quad * 8];
#pragma unroll
    for (int ni = 0; ni < 2; ++ni)
      bfr[ni] = *(const bf16x8*)&Bs[(quad * 256 + wave * 32 + ni * 16 + l15) * 8];
    __syncthreads();  // frags in regs
    if (k0c < 7) {
#pragma unroll
      for (int i = 0; i < 2; ++i) {
        const int sb = wave * 128 + i * 64;
        const unsigned short* g =
            Wcb_t + ((size_t)(k0c + 1) * 1024 + sb + lane) * 8;
        __builtin_amdgcn_global_load_lds((gp1_t)g, (lp3_t)(Bs + sb * 8), 16, 0, 0);
      }
    }
#pragma unroll
    for (int mi = 0; mi < 2; ++mi)
#pragma unroll
      for (int ni = 0; ni < 2; ++ni)
        acc2[mi][ni] = __builtin_amdgcn_mfma_f32_16x16x32_bf16(
            bfr[ni], af[mi], acc2[mi][ni], 0, 0, 0);
    __syncthreads();
  }

  // stage-2 epilogue: out = a*(acc2+bcomb)+bout, permuted (b,c,l,d) store
#pragma unroll
  for (int mi = 0; mi < 2; ++mi) {
    const int rl = mi * 16 + l15;
    const int r = rt0 + rl;
    const int c = r & 15, p = r >> 4;
    const int l = p & 511, b = p >> 9;
    const float av = af_s[rl];
    float* orow = out + ((size_t)(b * 16 + c) * 512 + l) * 256;
#pragma unroll
    for (int ni = 0; ni < 2; ++ni) {
      const int n = wave * 32 + ni * 16 + quad * 4;
      const float4 bc = *(const float4*)(bcomb + n);
      const float4 bo = *(const float4*)(bout + n);
      float4 o;
      o.x = fmaf(av, acc2[mi][ni][0] + bc.x, bo.x);
      o.y = fmaf(av, acc2[mi][ni][1] + bc.y, bo.y);
      o.z = fmaf(av, acc2[mi][ni][2] + bc.z, bo.z);
      o.w = fmaf(av, acc2[mi][ni][3] + bc.w, bo.w);
      *(float4*)(orow + n) = o;
    }
  }
}

extern "C" void kernel_launch(void* const* d_in, const int* in_sizes, int n_in,
                              void* d_out, int out_size, void* d_ws, size_t ws_size,
                              hipStream_t stream) {
  (void)in_sizes; (void)n_in; (void)out_size; (void)ws_size;
  const float* x    = (const float*)d_in[0];
  const float* Wqkv = (const float*)d_in[1];
  const float* bqkv = (const float*)d_in[2];
  const float* Vw   = (const float*)d_in[3];
  const float* bh   = (const float*)d_in[5];
  const float* Wout = (const float*)d_in[7];
  const float* bout = (const float*)d_in[8];
  float* out = (float*)d_out;

  // ws: bcomb fp32 256 | Wqb_t bf16 512*256 | Wcb_t bf16 256*256
  float* bcomb = (float*)d_ws;
  unsigned short* Wqb_t = (unsigned short*)(bcomb + 256);
  unsigned short* Wcb_t = Wqb_t + (size_t)512 * 256;

  ca_prep_kernel<<<dim3(320), dim3(256), 0, stream>>>(
      Wqkv, Wout, bqkv, Wqb_t, Wcb_t, bcomb);
  ca_fused<<<dim3(2048), dim3(512), 0, stream>>>(
      x, Wqb_t, Wcb_t, bqkv, bh, Vw, bcomb, bout, out);
}